// Round 2
// baseline (76.311 us; speedup 1.0000x reference)
//
#include <hip/hip_runtime.h>
#include <hip/hip_bf16.h>

#define N_NODES 207
#define N_EDGES 1722
#define BATCH   64
#define BLOCK   256

// One block per batch row. Laplacians are never materialized:
//   reaction[b,n] = in[b,n]*csr[n] - sum_{k: edge_i[k]==n} w_r[k]*in[b,edge_j[k]] + bias_r[n]
//   csr[c]        = sum_{k: edge_j[k]==c} w_r[k]          (W.sum(axis=0))
//   diffusion[b,n]= in[b,n]*csd[n] - sum_{k: edge_j[k]==n} w_d[k]*in[b,edge_i[k]] + bias_d[n]
//   csd[c]        = sum_{k: edge_i[k]==c} w_d[k]
//   out = tanh(reaction) + diffusion + in
// Column sums are batch-invariant but recomputed per block (1722 LDS atomics
// is far cheaper than a second kernel launch at this size).
// All float buffers are float32 (reference dtype); edges are int32.
__global__ __launch_bounds__(BLOCK) void reaction_diffusion_kernel(
    const float* __restrict__ input,    // [B, N]
    const float* __restrict__ w_r,      // [E]
    const float* __restrict__ w_d,      // [E]
    const float* __restrict__ bias_r,   // [N]
    const float* __restrict__ bias_d,   // [N]
    const int* __restrict__ edge_i,     // [E]
    const int* __restrict__ edge_j,     // [E]
    float* __restrict__ out)            // [B, N]
{
    __shared__ float s_in[N_NODES];
    __shared__ float s_reac[N_NODES];
    __shared__ float s_diff[N_NODES];
    __shared__ float s_csr[N_NODES];
    __shared__ float s_csd[N_NODES];

    const int b   = blockIdx.x;
    const int tid = threadIdx.x;

    for (int n = tid; n < N_NODES; n += BLOCK) {
        s_in[n]   = input[b * N_NODES + n];
        s_reac[n] = 0.0f;
        s_diff[n] = 0.0f;
        s_csr[n]  = 0.0f;
        s_csd[n]  = 0.0f;
    }
    __syncthreads();

    for (int k = tid; k < N_EDGES; k += BLOCK) {
        const int   i  = edge_i[k];
        const int   j  = edge_j[k];
        const float wr = w_r[k];
        const float wd = w_d[k];
        atomicAdd(&s_reac[i], wr * s_in[j]);   // gather term of reaction at node i
        atomicAdd(&s_csr[j],  wr);             // column sum of W_r
        atomicAdd(&s_diff[j], wd * s_in[i]);   // gather term of diffusion at node j
        atomicAdd(&s_csd[i],  wd);             // column sum of W_d
    }
    __syncthreads();

    for (int n = tid; n < N_NODES; n += BLOCK) {
        const float x = s_in[n];
        const float r = x * s_csr[n] - s_reac[n] + bias_r[n];
        const float d = x * s_csd[n] - s_diff[n] + bias_d[n];
        out[b * N_NODES + n] = tanhf(r) + d + x;
    }
}

extern "C" void kernel_launch(void* const* d_in, const int* in_sizes, int n_in,
                              void* d_out, int out_size, void* d_ws, size_t ws_size,
                              hipStream_t stream) {
    const float* input  = (const float*)d_in[0];
    const float* w_r    = (const float*)d_in[1];
    const float* w_d    = (const float*)d_in[2];
    const float* bias_r = (const float*)d_in[3];
    const float* bias_d = (const float*)d_in[4];
    const int*   edge_i = (const int*)d_in[5];
    const int*   edge_j = (const int*)d_in[6];
    float*       out    = (float*)d_out;

    reaction_diffusion_kernel<<<BATCH, BLOCK, 0, stream>>>(
        input, w_r, w_d, bias_r, bias_d, edge_i, edge_j, out);
}